// Round 12
// baseline (333.954 us; speedup 1.0000x reference)
//
#include <hip/hip_runtime.h>

#define VOCAB   50000
#define LDIM    8921
#define DDIM    300
#define DPAD    320
#define KSZ     10
#define BATCH   8
#define TSEQ    2048
#define PADL    9
#define TPRIME  2057
#define TPADDED 2066
#define LPAD    8928

// ---- attn tiling
#define TSTG    32                 // t rows per LDS tile
#define NTT     65                 // ceil(TPRIME/TSTG)
#define TALLOC  (NTT * TSTG)       // 2080 h rows per batch (tail rows zeroed by conv)
#define LBLK    70                 // ceil(LDIM/128) l-blocks

typedef short s8v __attribute__((ext_vector_type(8)));   // 8 x bf16 bits
typedef float f4v __attribute__((ext_vector_type(4)));

typedef const __attribute__((address_space(1))) unsigned int* gas_ptr;
typedef __attribute__((address_space(3))) unsigned int* las_ptr;

__device__ inline unsigned short f2bf(float f) {
  union { float f; unsigned u; } v; v.f = f;
  unsigned r = v.u + 0x7FFF + ((v.u >> 16) & 1);
  return (unsigned short)(r >> 16);
}

// ---- K1: conv weight transform + U transform (fused prep)
__global__ __launch_bounds__(256) void prep_kernel(
    const float* __restrict__ w, const float* __restrict__ U,
    unsigned short* __restrict__ wT, unsigned short* __restrict__ Ub) {
  int bid = blockIdx.x;
  if (bid < KSZ * DPAD) {
    int k = bid / DPAD, o = bid % DPAD;
    for (int i = threadIdx.x; i < DPAD; i += 256) {
      float v = (o < DDIM && i < DDIM) ? w[((size_t)o * DDIM + i) * KSZ + k] : 0.0f;
      wT[((size_t)k * DPAD + o) * DPAD + i] = f2bf(v);
    }
  } else {
    int l = bid - KSZ * DPAD;
    for (int d = threadIdx.x; d < DPAD; d += 256) {
      float v = (l < LDIM && d < DDIM) ? U[(size_t)l * DDIM + d] : 0.0f;
      Ub[(size_t)l * DPAD + d] = f2bf(v);
    }
  }
}

// ---- K2: conv via MFMA, fused embedding gather (r10 proven), now 8-WAVE.
// r12: conv was the hidden ~100-115us slice (r2 direct evidence: ~1500cyc/iter
// at 1 wave/SIMD vs ~300 ideal — pure latency exposure; r5 kept that chain).
// 512 threads = 8 waves: 4 o-quadrants x 2 t-groups (nf {0,1,2} / {3,4},
// wave-uniform branch, static acc sizes). Each SIMD hosts TWO independent
// chains -> exposed latency ~halves; MFMA issue per SIMD unchanged.
// Avoids r3 (NO min-wave clause: cap stays 256 VGPR at 2 waves/SIMD, live
// set ~140) and r4 (grid stays 208 = 1 block/CU, zero quantization).
#define CTN 80
#define CROWS 89          // CTN + KSZ - 1
#define CSTRIDE 328       // 656B/row -> benign 2-way conflicts
__global__ __launch_bounds__(512) void conv_mfma_kernel(
    const int* __restrict__ ids, const float* __restrict__ embed_w,
    const unsigned short* __restrict__ wT,
    const float* __restrict__ bias, unsigned short* __restrict__ h) {
  __shared__ unsigned short xls[CROWS * CSTRIDE];   // 58384 B
  int b = blockIdx.x & 7, tb = blockIdx.x >> 3;     // grid 208 = 8 x 26
  int t0 = tb * CTN;
  int tid = threadIdx.x;
  {
    const int* idsb = ids + b * TSEQ;
    for (int idx = tid; idx < CROWS * 40; idx += 512) {
      int rr = idx / 40, c8 = idx % 40;
      int tau = t0 + rr;
      bool inr = (tau >= PADL) && (tau < PADL + TSEQ);
      unsigned short pk[8];
      if (inr) {
        int row = idsb[tau - PADL];
        const float* src = embed_w + (size_t)row * DDIM + c8 * 8;
        float4 lo = (c8 * 8 + 3 < DDIM) ? *(const float4*)&src[0] : make_float4(0, 0, 0, 0);
        float4 hi = (c8 * 8 + 7 < DDIM) ? *(const float4*)&src[4] : make_float4(0, 0, 0, 0);
        pk[0] = f2bf(lo.x); pk[1] = f2bf(lo.y); pk[2] = f2bf(lo.z); pk[3] = f2bf(lo.w);
        pk[4] = f2bf(hi.x); pk[5] = f2bf(hi.y); pk[6] = f2bf(hi.z); pk[7] = f2bf(hi.w);
      } else {
#pragma unroll
        for (int e = 0; e < 8; ++e) pk[e] = 0;
      }
      *(int4*)&xls[rr * CSTRIDE + c8 * 8] = *(const int4*)pk;
    }
  }
  __syncthreads();
  int ww = tid >> 6, lane = tid & 63;
  int wo = ww & 3, wt = ww >> 2;        // 4 o-quadrants x 2 t-groups
  int l15 = lane & 15, quad = lane >> 4;
  int ob = wo * 80;
  // A-frag (kc,it,mf) at wl[kc*DPAD*DPAD + mf*16*DPAD + it*32]
  const unsigned short* wl = wT + (size_t)(ob + l15) * DPAD + quad * 8;

#define CONV_BODY(NFN, NF0)                                                    \
  {                                                                            \
    f4v acc[5][NFN];                                                           \
    _Pragma("unroll")                                                          \
    for (int mf = 0; mf < 5; ++mf) {                                           \
      float bv[4];                                                             \
      _Pragma("unroll")                                                        \
      for (int rr = 0; rr < 4; ++rr) {                                         \
        int o = ob + mf * 16 + quad * 4 + rr;                                  \
        bv[rr] = (o < DDIM) ? bias[o] : 0.0f;                                  \
      }                                                                        \
      _Pragma("unroll")                                                        \
      for (int nf = 0; nf < NFN; ++nf) {                                       \
        acc[mf][nf][0] = bv[0]; acc[mf][nf][1] = bv[1];                        \
        acc[mf][nf][2] = bv[2]; acc[mf][nf][3] = bv[3];                        \
      }                                                                        \
    }                                                                          \
    s8v Aping[5], Apong[5];                                                    \
    _Pragma("unroll")                                                          \
    for (int mf = 0; mf < 5; ++mf)                                             \
      Aping[mf] = *(const s8v*)&wl[mf * 16 * DPAD];                            \
    _Pragma("unroll")                                                          \
    for (int mf = 0; mf < 5; ++mf)                                             \
      Apong[mf] = *(const s8v*)&wl[mf * 16 * DPAD + 32];                       \
    for (int ii = 0; ii < 100; ii += 2) {                                      \
      {                                                                        \
        int kc = ii / 10, it = ii % 10;                                        \
        s8v Bv[NFN];                                                           \
        _Pragma("unroll")                                                      \
        for (int nf = 0; nf < NFN; ++nf)                                       \
          Bv[nf] = *(const s8v*)&xls[((NF0 + nf) * 16 + l15 + kc) * CSTRIDE + it * 32 + quad * 8]; \
        _Pragma("unroll")                                                      \
        for (int mf = 0; mf < 5; ++mf)                                         \
          _Pragma("unroll")                                                    \
          for (int nf = 0; nf < NFN; ++nf)                                     \
            acc[mf][nf] = __builtin_amdgcn_mfma_f32_16x16x32_bf16(Aping[mf], Bv[nf], acc[mf][nf], 0, 0, 0); \
        int p = ii + 2;                                                        \
        if (p < 100) {                                                         \
          int kp = p / 10, itp = p % 10;                                       \
          const unsigned short* wp = wl + (size_t)kp * (DPAD * DPAD) + itp * 32; \
          _Pragma("unroll")                                                    \
          for (int mf = 0; mf < 5; ++mf)                                       \
            Aping[mf] = *(const s8v*)&wp[mf * 16 * DPAD];                      \
        }                                                                      \
      }                                                                        \
      {                                                                        \
        int kc = (ii + 1) / 10, it = (ii + 1) % 10;                            \
        s8v Bv[NFN];                                                           \
        _Pragma("unroll")                                                      \
        for (int nf = 0; nf < NFN; ++nf)                                       \
          Bv[nf] = *(const s8v*)&xls[((NF0 + nf) * 16 + l15 + kc) * CSTRIDE + it * 32 + quad * 8]; \
        _Pragma("unroll")                                                      \
        for (int mf = 0; mf < 5; ++mf)                                         \
          _Pragma("unroll")                                                    \
          for (int nf = 0; nf < NFN; ++nf)                                     \
            acc[mf][nf] = __builtin_amdgcn_mfma_f32_16x16x32_bf16(Apong[mf], Bv[nf], acc[mf][nf], 0, 0, 0); \
        int p = ii + 3;                                                        \
        if (p < 100) {                                                         \
          int kp = p / 10, itp = p % 10;                                       \
          const unsigned short* wp = wl + (size_t)kp * (DPAD * DPAD) + itp * 32; \
          _Pragma("unroll")                                                    \
          for (int mf = 0; mf < 5; ++mf)                                       \
            Apong[mf] = *(const s8v*)&wp[mf * 16 * DPAD];                      \
        }                                                                      \
      }                                                                        \
    }                                                                          \
    _Pragma("unroll")                                                          \
    for (int mf = 0; mf < 5; ++mf) {                                           \
      int obase = ob + mf * 16 + quad * 4;                                     \
      _Pragma("unroll")                                                        \
      for (int nf = 0; nf < NFN; ++nf) {                                       \
        int t = t0 + (NF0 + nf) * 16 + l15;                                    \
        bool live = t < TPRIME;                                                \
        unsigned short pk[4];                                                  \
        _Pragma("unroll")                                                      \
        for (int rr = 0; rr < 4; ++rr)                                         \
          pk[rr] = live ? f2bf(fmaxf(acc[mf][nf][rr], 0.0f)) : (unsigned short)0; \
        *(uint2*)&h[((size_t)b * TALLOC + t) * DPAD + obase] = *(uint2*)pk;    \
      }                                                                        \
    }                                                                          \
  }

  if (wt == 0) {
    CONV_BODY(3, 0)       // t rows t0+0 .. t0+47 (+kc halo reads to row 71)
  } else {
    CONV_BODY(2, 3)       // t rows t0+48 .. t0+79 (+kc halo reads to row 88)
  }
#undef CONV_BODY
}

// ---- K3: scores (U . h) via MFMA + fused softmax-weighted mean.
// FROZEN r5/r6 local optimum (119us; best of 6 structural attempts — r6
// tweaks null, r7 T15 spilled, r8 8-wave +13, r9 no-LDS +330, r10 dist-2
// +32). 4 waves, depth-1 DMA double-buffer, vmcnt(0)+barrier per tile, all
// 560 blocks co-resident at (256,3). A[2][10] in AGPRs. Unmasked softmax
// (tail h rows exact zeros -> e=1) + (-23) phantom correction; setprio.
__global__ __launch_bounds__(256, 3) void attn_mfma_kernel(
    const unsigned short* __restrict__ h, const unsigned short* __restrict__ Ub,
    const float* __restrict__ fcb, float* __restrict__ out) {
  __shared__ unsigned short hls[2 * TSTG * DPAD];   // 2 x 10240 elems = 40960B
  int b = blockIdx.x & 7, lb = blockIdx.x >> 3;
  int tid = threadIdx.x;
  int w = tid >> 6, lane = tid & 63;
  int l15 = lane & 15, quad = lane >> 4;
  const unsigned short* hb = h + (size_t)b * TALLOC * DPAD;

  // A fragments (U): wave covers 32 l-rows
  s8v A[2][10];
  {
    int lr0 = lb * 128 + w * 32 + l15;
#pragma unroll
    for (int mf = 0; mf < 2; ++mf) {
      int lr = lr0 + mf * 16;
      if (lr >= LPAD) lr = LPAD - 1;          // clamped rows masked at store
      const unsigned short* up = Ub + (size_t)lr * DPAD + quad * 8;
#pragma unroll
      for (int kc = 0; kc < 10; ++kc)
        A[mf][kc] = *(const s8v*)&up[kc * 32];
    }
  }

  // DMA staging map: wave w fills LDS elems [w*2560, w*2560+2560) in 5 x 1KB.
  // lane's LDS chunk g = w*320 + j*64 + lane -> row r = g/40, chunk c = g%40;
  // global source chunk = c ^ (r&7)  (involution, same XOR on read side)
  int srcoff[5];
#pragma unroll
  for (int j = 0; j < 5; ++j) {
    int g = w * 320 + j * 64 + lane;
    int r = g / 40, c = g % 40;
    srcoff[j] = r * DPAD + ((c ^ (r & 7)) * 8);
  }

  // prologue: DMA tile 0 -> buf0
#pragma unroll
  for (int j = 0; j < 5; ++j)
    __builtin_amdgcn_global_load_lds((gas_ptr)(const void*)(hb + srcoff[j]),
                                     (las_ptr)(void*)&hls[w * 2560 + j * 512],
                                     16, 0, 0);
  asm volatile("s_waitcnt vmcnt(0)" ::: "memory");
  __builtin_amdgcn_s_barrier();

  float se[2][4], sw[2][4];
#pragma unroll
  for (int mf = 0; mf < 2; ++mf)
#pragma unroll
    for (int r = 0; r < 4; ++r) { se[mf][r] = 0.0f; sw[mf][r] = 0.0f; }

  int xr8 = (l15 & 7) * 8;            // read-side XOR (elem units)
  int rowb0 = l15 * DPAD;             // nf=0 row base
  int rowb1 = (16 + l15) * DPAD;      // nf=1 row base
  int bufsel = 0;
  const f4v vzero = {0.0f, 0.0f, 0.0f, 0.0f};
  for (int t = 0; t < NTT; ++t) {
    // issue DMA for tile t+1 into the other buffer (latency hidden by compute)
    if (t + 1 < NTT) {
      const unsigned short* src = hb + (size_t)(t + 1) * TSTG * DPAD;
      int dstb = (bufsel ^ 1) * 10240 + w * 2560;
#pragma unroll
      for (int j = 0; j < 5; ++j)
        __builtin_amdgcn_global_load_lds((gas_ptr)(const void*)(src + srcoff[j]),
                                         (las_ptr)(void*)&hls[dstb + j * 512],
                                         16, 0, 0);
    }
    const unsigned short* bufc = &hls[bufsel * 10240];
    f4v a00, a01, a10, a11;
    __builtin_amdgcn_s_setprio(1);
    {
      int ko = (quad * 8) ^ xr8;
      s8v Bv0 = *(const s8v*)&bufc[rowb0 + ko];
      s8v Bv1 = *(const s8v*)&bufc[rowb1 + ko];
      a00 = __builtin_amdgcn_mfma_f32_16x16x32_bf16(A[0][0], Bv0, vzero, 0, 0, 0);
      a01 = __builtin_amdgcn_mfma_f32_16x16x32_bf16(A[0][0], Bv1, vzero, 0, 0, 0);
      a10 = __builtin_amdgcn_mfma_f32_16x16x32_bf16(A[1][0], Bv0, vzero, 0, 0, 0);
      a11 = __builtin_amdgcn_mfma_f32_16x16x32_bf16(A[1][0], Bv1, vzero, 0, 0, 0);
    }
#pragma unroll
    for (int kc = 1; kc < 10; ++kc) {
      int ko = (kc * 32 + quad * 8) ^ xr8;
      s8v Bv0 = *(const s8v*)&bufc[rowb0 + ko];
      s8v Bv1 = *(const s8v*)&bufc[rowb1 + ko];
      a00 = __builtin_amdgcn_mfma_f32_16x16x32_bf16(A[0][kc], Bv0, a00, 0, 0, 0);
      a01 = __builtin_amdgcn_mfma_f32_16x16x32_bf16(A[0][kc], Bv1, a01, 0, 0, 0);
      a10 = __builtin_amdgcn_mfma_f32_16x16x32_bf16(A[1][kc], Bv0, a10, 0, 0, 0);
      a11 = __builtin_amdgcn_mfma_f32_16x16x32_bf16(A[1][kc], Bv1, a11, 0, 0, 0);
    }
    __builtin_amdgcn_s_setprio(0);
    // unmasked fused softmax accumulation (tail h rows are exact zeros ->
    // s=0 -> e=1; corrected after the reduction)
#pragma unroll
    for (int r = 0; r < 4; ++r) {
      float s0 = a00[r], s1 = a01[r];
      float e0 = __expf(s0), e1 = __expf(s1);
      se[0][r] += e0 + e1;
      sw[0][r] = fmaf(e0, s0, sw[0][r]);
      sw[0][r] = fmaf(e1, s1, sw[0][r]);
      float s2 = a10[r], s3 = a11[r];
      float e2 = __expf(s2), e3 = __expf(s3);
      se[1][r] += e2 + e3;
      sw[1][r] = fmaf(e2, s2, sw[1][r]);
      sw[1][r] = fmaf(e3, s3, sw[1][r]);
    }
    // drain this iter's DMA (issued a full tile of compute ago), sync, swap
    asm volatile("s_waitcnt vmcnt(0)" ::: "memory");
    __builtin_amdgcn_s_barrier();
    bufsel ^= 1;
  }

  // reduce over the 16 t-columns (l15 lanes); subtract the 23 phantom columns
  // (TALLOC - TPRIME, each contributing exactly exp(0)=1) from the denominator.
#pragma unroll
  for (int mf = 0; mf < 2; ++mf)
#pragma unroll
    for (int r = 0; r < 4; ++r) {
      float a = se[mf][r], c = sw[mf][r];
#pragma unroll
      for (int off = 1; off < 16; off <<= 1) {
        a += __shfl_xor(a, off, 64);
        c += __shfl_xor(c, off, 64);
      }
      if (l15 == 0) {
        int l = lb * 128 + w * 32 + mf * 16 + quad * 4 + r;
        if (l < LDIM) out[(size_t)b * LDIM + l] = c / (a - 23.0f) + fcb[l];
      }
    }
}

extern "C" void kernel_launch(void* const* d_in, const int* in_sizes, int n_in,
                              void* d_out, int out_size, void* d_ws, size_t ws_size,
                              hipStream_t stream) {
  const int*   ids     = (const int*)d_in[0];
  const float* embed_w = (const float*)d_in[1];
  const float* conv_w  = (const float*)d_in[2];
  const float* conv_b  = (const float*)d_in[3];
  const float* U       = (const float*)d_in[4];
  const float* fc_bias = (const float*)d_in[5];
  float* out = (float*)d_out;

  unsigned char* p = (unsigned char*)d_ws;
  unsigned short* hb = (unsigned short*)p;                 p += (size_t)BATCH * TALLOC * DPAD * 2;
  unsigned short* wT = (unsigned short*)p;                 p += (size_t)KSZ * DPAD * DPAD * 2;
  unsigned short* Ub = (unsigned short*)p;

  hipLaunchKernelGGL(prep_kernel, dim3(KSZ * DPAD + LPAD), dim3(256), 0, stream,
                     conv_w, U, wT, Ub);
  hipLaunchKernelGGL(conv_mfma_kernel, dim3(BATCH * 26), dim3(512), 0, stream,
                     ids, embed_w, wT, conv_b, hb);
  hipLaunchKernelGGL(attn_mfma_kernel, dim3(BATCH * LBLK), dim3(256), 0, stream,
                     hb, Ub, fc_bias, out);
}

// Round 14
// 290.693 us; speedup vs baseline: 1.1488x; 1.1488x over previous
//
#include <hip/hip_runtime.h>

#define VOCAB   50000
#define LDIM    8921
#define DDIM    300
#define DPAD    320
#define KSZ     10
#define BATCH   8
#define TSEQ    2048
#define PADL    9
#define TPRIME  2057
#define TPADDED 2066
#define LPAD    8928

// ---- attn tiling
#define TSTG    32                 // t rows per LDS tile
#define NTT     65                 // ceil(TPRIME/TSTG)
#define TALLOC  (NTT * TSTG)       // 2080 h rows per batch (tail rows zeroed by conv)
#define LBLK    70                 // ceil(LDIM/128) l-blocks

typedef short s8v __attribute__((ext_vector_type(8)));   // 8 x bf16 bits
typedef float f4v __attribute__((ext_vector_type(4)));

typedef const __attribute__((address_space(1))) unsigned int* gas_ptr;
typedef __attribute__((address_space(3))) unsigned int* las_ptr;

__device__ inline unsigned short f2bf(float f) {
  union { float f; unsigned u; } v; v.f = f;
  unsigned r = v.u + 0x7FFF + ((v.u >> 16) & 1);
  return (unsigned short)(r >> 16);
}

// ---- K1: conv weight transform + U transform (fused prep)
__global__ __launch_bounds__(256) void prep_kernel(
    const float* __restrict__ w, const float* __restrict__ U,
    unsigned short* __restrict__ wT, unsigned short* __restrict__ Ub) {
  int bid = blockIdx.x;
  if (bid < KSZ * DPAD) {
    int k = bid / DPAD, o = bid % DPAD;
    for (int i = threadIdx.x; i < DPAD; i += 256) {
      float v = (o < DDIM && i < DDIM) ? w[((size_t)o * DDIM + i) * KSZ + k] : 0.0f;
      wT[((size_t)k * DPAD + o) * DPAD + i] = f2bf(v);
    }
  } else {
    int l = bid - KSZ * DPAD;
    for (int d = threadIdx.x; d < DPAD; d += 256) {
      float v = (l < LDIM && d < DDIM) ? U[(size_t)l * DDIM + d] : 0.0f;
      Ub[(size_t)l * DPAD + d] = f2bf(v);
    }
  }
}

// ---- K2: conv via MFMA, fused embedding gather, K-SPLIT ACROSS WAVES.
// Decomposition (r11 vs r12 delta): conv ~82us = 100 serial K-iters x ~1970cyc,
// latency-paced by the per-wave A-prefetch chain. Split the 100 iters over
// 2 k-half waves (50 each) -> block time ~halves if chain is per-wave latency.
// 512 threads = 4 o-quadrants x 2 k-halves; 2-phase LDS reduction (overlay
// 2x25.6KB f32 on dead xls).
// LAUNCH-BOUNDS LEDGER (the critical knob): (512,4)->128-cap demotion (r3);
// bare (512)->occupancy heuristic demotes to 60 VGPR (r12); (512,1)->allows
// >256 VGPR -> 8-wave block unlaunchable, ABORT (r13). (512,2) is the unique
// correct setting: cap 256 = the 2-waves/SIMD geometry of 1-block/CU x 512t.
#define CTN 80
#define CROWS 89          // CTN + KSZ - 1
#define CSTRIDE 328       // 656B/row -> benign 2-way conflicts
__global__ __launch_bounds__(512, 2) void conv_mfma_kernel(
    const int* __restrict__ ids, const float* __restrict__ embed_w,
    const unsigned short* __restrict__ wT,
    const float* __restrict__ bias, unsigned short* __restrict__ h) {
  __shared__ unsigned short xls[CROWS * CSTRIDE];   // 58384 B
  int b = blockIdx.x & 7, tb = blockIdx.x >> 3;     // grid 208 = 8 x 26
  int t0 = tb * CTN;
  int tid = threadIdx.x;
  {
    const int* idsb = ids + b * TSEQ;
    for (int idx = tid; idx < CROWS * 40; idx += 512) {
      int rr = idx / 40, c8 = idx % 40;
      int tau = t0 + rr;
      bool inr = (tau >= PADL) && (tau < PADL + TSEQ);
      unsigned short pk[8];
      if (inr) {
        int row = idsb[tau - PADL];
        const float* src = embed_w + (size_t)row * DDIM + c8 * 8;
        float4 lo = (c8 * 8 + 3 < DDIM) ? *(const float4*)&src[0] : make_float4(0, 0, 0, 0);
        float4 hi = (c8 * 8 + 7 < DDIM) ? *(const float4*)&src[4] : make_float4(0, 0, 0, 0);
        pk[0] = f2bf(lo.x); pk[1] = f2bf(lo.y); pk[2] = f2bf(lo.z); pk[3] = f2bf(lo.w);
        pk[4] = f2bf(hi.x); pk[5] = f2bf(hi.y); pk[6] = f2bf(hi.z); pk[7] = f2bf(hi.w);
      } else {
#pragma unroll
        for (int e = 0; e < 8; ++e) pk[e] = 0;
      }
      *(int4*)&xls[rr * CSTRIDE + c8 * 8] = *(const int4*)pk;
    }
  }
  __syncthreads();
  int ww = tid >> 6, lane = tid & 63;
  int wo = ww & 3, wk = ww >> 2;        // 4 o-quadrants x 2 k-halves
  int l15 = lane & 15, quad = lane >> 4;
  int ob = wo * 80;
  f4v acc[5][5];
#pragma unroll
  for (int mf = 0; mf < 5; ++mf) {
    float bv[4];
#pragma unroll
    for (int rr = 0; rr < 4; ++rr) {
      int o = ob + mf * 16 + quad * 4 + rr;
      bv[rr] = (wk == 0 && o < DDIM) ? bias[o] : 0.0f;   // bias only in half 0
    }
#pragma unroll
    for (int nf = 0; nf < 5; ++nf) {
      acc[mf][nf][0] = bv[0]; acc[mf][nf][1] = bv[1];
      acc[mf][nf][2] = bv[2]; acc[mf][nf][3] = bv[3];
    }
  }
  // A-frag (kc,it,mf) at wl[kc*DPAD*DPAD + mf*16*DPAD + it*32]
  const unsigned short* wl = wT + (size_t)(ob + l15) * DPAD + quad * 8;
  int ii0 = wk * 50, iiE = ii0 + 50;    // this wave's K-iteration range
  s8v Aping[5], Apong[5];
  {
    int kc0 = ii0 / 10;
#pragma unroll
    for (int mf = 0; mf < 5; ++mf)
      Aping[mf] = *(const s8v*)&wl[(size_t)kc0 * (DPAD * DPAD) + mf * 16 * DPAD];        // (kc0,0)
#pragma unroll
    for (int mf = 0; mf < 5; ++mf)
      Apong[mf] = *(const s8v*)&wl[(size_t)kc0 * (DPAD * DPAD) + mf * 16 * DPAD + 32];   // (kc0,1)
  }
  for (int ii = ii0; ii < iiE; ii += 2) {
    // ---- even sub-iter: frags (ii) in Aping
    {
      int kc = ii / 10, it = ii % 10;
      s8v Bv[5];
#pragma unroll
      for (int nf = 0; nf < 5; ++nf)
        Bv[nf] = *(const s8v*)&xls[(nf * 16 + l15 + kc) * CSTRIDE + it * 32 + quad * 8];
#pragma unroll
      for (int mf = 0; mf < 5; ++mf)
#pragma unroll
        for (int nf = 0; nf < 5; ++nf)
          acc[mf][nf] = __builtin_amdgcn_mfma_f32_16x16x32_bf16(Aping[mf], Bv[nf], acc[mf][nf], 0, 0, 0);
      int p = ii + 2;
      if (p < iiE) {
        int kp = p / 10, itp = p % 10;
        const unsigned short* wp = wl + (size_t)kp * (DPAD * DPAD) + itp * 32;
#pragma unroll
        for (int mf = 0; mf < 5; ++mf) Aping[mf] = *(const s8v*)&wp[mf * 16 * DPAD];
      }
    }
    // ---- odd sub-iter: frags (ii+1) in Apong
    {
      int kc = (ii + 1) / 10, it = (ii + 1) % 10;
      s8v Bv[5];
#pragma unroll
      for (int nf = 0; nf < 5; ++nf)
        Bv[nf] = *(const s8v*)&xls[(nf * 16 + l15 + kc) * CSTRIDE + it * 32 + quad * 8];
#pragma unroll
      for (int mf = 0; mf < 5; ++mf)
#pragma unroll
        for (int nf = 0; nf < 5; ++nf)
          acc[mf][nf] = __builtin_amdgcn_mfma_f32_16x16x32_bf16(Apong[mf], Bv[nf], acc[mf][nf], 0, 0, 0);
      int p = ii + 3;
      if (p < iiE) {
        int kp = p / 10, itp = p % 10;
        const unsigned short* wp = wl + (size_t)kp * (DPAD * DPAD) + itp * 32;
#pragma unroll
        for (int mf = 0; mf < 5; ++mf) Apong[mf] = *(const s8v*)&wp[mf * 16 * DPAD];
      }
    }
  }
  // ---- 2-phase k-half reduction: overlay f32 buffer on the dead xls.
  // Phase p handles o-quadrants {2p, 2p+1} via slots {0,1} (2x25.6KB <= 58KB).
  float* red = (float*)xls;
#pragma unroll
  for (int p = 0; p < 2; ++p) {
    __syncthreads();
    if (wk == 1 && (wo >> 1) == p) {
      float* dst = red + (wo & 1) * 6400;
#pragma unroll
      for (int mf = 0; mf < 5; ++mf)
#pragma unroll
        for (int nf = 0; nf < 5; ++nf)
#pragma unroll
          for (int rr = 0; rr < 4; ++rr)
            dst[(mf * 16 + quad * 4 + rr) * 80 + nf * 16 + l15] = acc[mf][nf][rr];
    }
    __syncthreads();
    if (wk == 0 && (wo >> 1) == p) {
      const float* srcp = red + (wo & 1) * 6400;
#pragma unroll
      for (int mf = 0; mf < 5; ++mf) {
        int obase = ob + mf * 16 + quad * 4;
#pragma unroll
        for (int nf = 0; nf < 5; ++nf) {
          int t = t0 + nf * 16 + l15;          // always < TALLOC (26x80 exact)
          bool live = t < TPRIME;
          unsigned short pk[4];
#pragma unroll
          for (int rr = 0; rr < 4; ++rr) {
            float v = acc[mf][nf][rr] + srcp[(mf * 16 + quad * 4 + rr) * 80 + nf * 16 + l15];
            pk[rr] = live ? f2bf(fmaxf(v, 0.0f)) : (unsigned short)0;
          }
          *(uint2*)&h[((size_t)b * TALLOC + t) * DPAD + obase] = *(uint2*)pk;
        }
      }
    }
  }
}

// ---- K3: scores (U . h) via MFMA + fused softmax-weighted mean.
// FROZEN r5/r6/r11 local optimum (119us; best of 6 structural attempts — r6
// tweaks null, r7 T15 spilled, r8 8-wave +13, r9 no-LDS +330, r10 dist-2
// +32). 4 waves, depth-1 DMA double-buffer, vmcnt(0)+barrier per tile, all
// 560 blocks co-resident at (256,3). A[2][10] in AGPRs. Unmasked softmax
// (tail h rows exact zeros -> e=1) + (-23) phantom correction; setprio.
__global__ __launch_bounds__(256, 3) void attn_mfma_kernel(
    const unsigned short* __restrict__ h, const unsigned short* __restrict__ Ub,
    const float* __restrict__ fcb, float* __restrict__ out) {
  __shared__ unsigned short hls[2 * TSTG * DPAD];   // 2 x 10240 elems = 40960B
  int b = blockIdx.x & 7, lb = blockIdx.x >> 3;
  int tid = threadIdx.x;
  int w = tid >> 6, lane = tid & 63;
  int l15 = lane & 15, quad = lane >> 4;
  const unsigned short* hb = h + (size_t)b * TALLOC * DPAD;

  // A fragments (U): wave covers 32 l-rows
  s8v A[2][10];
  {
    int lr0 = lb * 128 + w * 32 + l15;
#pragma unroll
    for (int mf = 0; mf < 2; ++mf) {
      int lr = lr0 + mf * 16;
      if (lr >= LPAD) lr = LPAD - 1;          // clamped rows masked at store
      const unsigned short* up = Ub + (size_t)lr * DPAD + quad * 8;
#pragma unroll
      for (int kc = 0; kc < 10; ++kc)
        A[mf][kc] = *(const s8v*)&up[kc * 32];
    }
  }

  // DMA staging map: wave w fills LDS elems [w*2560, w*2560+2560) in 5 x 1KB.
  // lane's LDS chunk g = w*320 + j*64 + lane -> row r = g/40, chunk c = g%40;
  // global source chunk = c ^ (r&7)  (involution, same XOR on read side)
  int srcoff[5];
#pragma unroll
  for (int j = 0; j < 5; ++j) {
    int g = w * 320 + j * 64 + lane;
    int r = g / 40, c = g % 40;
    srcoff[j] = r * DPAD + ((c ^ (r & 7)) * 8);
  }

  // prologue: DMA tile 0 -> buf0
#pragma unroll
  for (int j = 0; j < 5; ++j)
    __builtin_amdgcn_global_load_lds((gas_ptr)(const void*)(hb + srcoff[j]),
                                     (las_ptr)(void*)&hls[w * 2560 + j * 512],
                                     16, 0, 0);
  asm volatile("s_waitcnt vmcnt(0)" ::: "memory");
  __builtin_amdgcn_s_barrier();

  float se[2][4], sw[2][4];
#pragma unroll
  for (int mf = 0; mf < 2; ++mf)
#pragma unroll
    for (int r = 0; r < 4; ++r) { se[mf][r] = 0.0f; sw[mf][r] = 0.0f; }

  int xr8 = (l15 & 7) * 8;            // read-side XOR (elem units)
  int rowb0 = l15 * DPAD;             // nf=0 row base
  int rowb1 = (16 + l15) * DPAD;      // nf=1 row base
  int bufsel = 0;
  const f4v vzero = {0.0f, 0.0f, 0.0f, 0.0f};
  for (int t = 0; t < NTT; ++t) {
    // issue DMA for tile t+1 into the other buffer (latency hidden by compute)
    if (t + 1 < NTT) {
      const unsigned short* src = hb + (size_t)(t + 1) * TSTG * DPAD;
      int dstb = (bufsel ^ 1) * 10240 + w * 2560;
#pragma unroll
      for (int j = 0; j < 5; ++j)
        __builtin_amdgcn_global_load_lds((gas_ptr)(const void*)(src + srcoff[j]),
                                         (las_ptr)(void*)&hls[dstb + j * 512],
                                         16, 0, 0);
    }
    const unsigned short* bufc = &hls[bufsel * 10240];
    f4v a00, a01, a10, a11;
    __builtin_amdgcn_s_setprio(1);
    {
      int ko = (quad * 8) ^ xr8;
      s8v Bv0 = *(const s8v*)&bufc[rowb0 + ko];
      s8v Bv1 = *(const s8v*)&bufc[rowb1 + ko];
      a00 = __builtin_amdgcn_mfma_f32_16x16x32_bf16(A[0][0], Bv0, vzero, 0, 0, 0);
      a01 = __builtin_amdgcn_mfma_f32_16x16x32_bf16(A[0][0], Bv1, vzero, 0, 0, 0);
      a10 = __builtin_amdgcn_mfma_f32_16x16x32_bf16(A[1][0], Bv0, vzero, 0, 0, 0);
      a11 = __builtin_amdgcn_mfma_f32_16x16x32_bf16(A[1][0], Bv1, vzero, 0, 0, 0);
    }
#pragma unroll
    for (int kc = 1; kc < 10; ++kc) {
      int ko = (kc * 32 + quad * 8) ^ xr8;
      s8v Bv0 = *(const s8v*)&bufc[rowb0 + ko];
      s8v Bv1 = *(const s8v*)&bufc[rowb1 + ko];
      a00 = __builtin_amdgcn_mfma_f32_16x16x32_bf16(A[0][kc], Bv0, a00, 0, 0, 0);
      a01 = __builtin_amdgcn_mfma_f32_16x16x32_bf16(A[0][kc], Bv1, a01, 0, 0, 0);
      a10 = __builtin_amdgcn_mfma_f32_16x16x32_bf16(A[1][kc], Bv0, a10, 0, 0, 0);
      a11 = __builtin_amdgcn_mfma_f32_16x16x32_bf16(A[1][kc], Bv1, a11, 0, 0, 0);
    }
    __builtin_amdgcn_s_setprio(0);
    // unmasked fused softmax accumulation (tail h rows are exact zeros ->
    // s=0 -> e=1; corrected after the reduction)
#pragma unroll
    for (int r = 0; r < 4; ++r) {
      float s0 = a00[r], s1 = a01[r];
      float e0 = __expf(s0), e1 = __expf(s1);
      se[0][r] += e0 + e1;
      sw[0][r] = fmaf(e0, s0, sw[0][r]);
      sw[0][r] = fmaf(e1, s1, sw[0][r]);
      float s2 = a10[r], s3 = a11[r];
      float e2 = __expf(s2), e3 = __expf(s3);
      se[1][r] += e2 + e3;
      sw[1][r] = fmaf(e2, s2, sw[1][r]);
      sw[1][r] = fmaf(e3, s3, sw[1][r]);
    }
    // drain this iter's DMA (issued a full tile of compute ago), sync, swap
    asm volatile("s_waitcnt vmcnt(0)" ::: "memory");
    __builtin_amdgcn_s_barrier();
    bufsel ^= 1;
  }

  // reduce over the 16 t-columns (l15 lanes); subtract the 23 phantom columns
  // (TALLOC - TPRIME, each contributing exactly exp(0)=1) from the denominator.
#pragma unroll
  for (int mf = 0; mf < 2; ++mf)
#pragma unroll
    for (int r = 0; r < 4; ++r) {
      float a = se[mf][r], c = sw[mf][r];
#pragma unroll
      for (int off = 1; off < 16; off <<= 1) {
        a += __shfl_xor(a, off, 64);
        c += __shfl_xor(c, off, 64);
      }
      if (l15 == 0) {
        int l = lb * 128 + w * 32 + mf * 16 + quad * 4 + r;
        if (l < LDIM) out[(size_t)b * LDIM + l] = c / (a - 23.0f) + fcb[l];
      }
    }
}

extern "C" void kernel_launch(void* const* d_in, const int* in_sizes, int n_in,
                              void* d_out, int out_size, void* d_ws, size_t ws_size,
                              hipStream_t stream) {
  const int*   ids     = (const int*)d_in[0];
  const float* embed_w = (const float*)d_in[1];
  const float* conv_w  = (const float*)d_in[2];
  const float* conv_b  = (const float*)d_in[3];
  const float* U       = (const float*)d_in[4];
  const float* fc_bias = (const float*)d_in[5];
  float* out = (float*)d_out;

  unsigned char* p = (unsigned char*)d_ws;
  unsigned short* hb = (unsigned short*)p;                 p += (size_t)BATCH * TALLOC * DPAD * 2;
  unsigned short* wT = (unsigned short*)p;                 p += (size_t)KSZ * DPAD * DPAD * 2;
  unsigned short* Ub = (unsigned short*)p;

  hipLaunchKernelGGL(prep_kernel, dim3(KSZ * DPAD + LPAD), dim3(256), 0, stream,
                     conv_w, U, wT, Ub);
  hipLaunchKernelGGL(conv_mfma_kernel, dim3(BATCH * 26), dim3(512), 0, stream,
                     ids, embed_w, wT, conv_b, hb);
  hipLaunchKernelGGL(attn_mfma_kernel, dim3(BATCH * LBLK), dim3(256), 0, stream,
                     hb, Ub, fc_bias, out);
}

// Round 15
// 284.854 us; speedup vs baseline: 1.1724x; 1.0205x over previous
//
#include <hip/hip_runtime.h>

#define VOCAB   50000
#define LDIM    8921
#define DDIM    300
#define DPAD    320
#define KSZ     10
#define BATCH   8
#define TSEQ    2048
#define PADL    9
#define TPRIME  2057
#define TPADDED 2066
#define LPAD    8928

// ---- attn tiling
#define TSTG    32                 // t rows per LDS tile
#define NTT     65                 // ceil(TPRIME/TSTG)
#define TALLOC  (NTT * TSTG)       // 2080 h rows per batch (tail rows zeroed by conv)
#define LBLK    70                 // ceil(LDIM/128) l-blocks

typedef short s8v __attribute__((ext_vector_type(8)));   // 8 x bf16 bits
typedef float f4v __attribute__((ext_vector_type(4)));

typedef const __attribute__((address_space(1))) unsigned int* gas_ptr;
typedef __attribute__((address_space(3))) unsigned int* las_ptr;

__device__ inline unsigned short f2bf(float f) {
  union { float f; unsigned u; } v; v.f = f;
  unsigned r = v.u + 0x7FFF + ((v.u >> 16) & 1);
  return (unsigned short)(r >> 16);
}

// ---- K1: conv weight transform + U transform (fused prep)
__global__ __launch_bounds__(256) void prep_kernel(
    const float* __restrict__ w, const float* __restrict__ U,
    unsigned short* __restrict__ wT, unsigned short* __restrict__ Ub) {
  int bid = blockIdx.x;
  if (bid < KSZ * DPAD) {
    int k = bid / DPAD, o = bid % DPAD;
    for (int i = threadIdx.x; i < DPAD; i += 256) {
      float v = (o < DDIM && i < DDIM) ? w[((size_t)o * DDIM + i) * KSZ + k] : 0.0f;
      wT[((size_t)k * DPAD + o) * DPAD + i] = f2bf(v);
    }
  } else {
    int l = bid - KSZ * DPAD;
    for (int d = threadIdx.x; d < DPAD; d += 256) {
      float v = (l < LDIM && d < DDIM) ? U[(size_t)l * DDIM + d] : 0.0f;
      Ub[(size_t)l * DPAD + d] = f2bf(v);
    }
  }
}

// ---- K2: conv via MFMA, fused embedding gather — r11 geometry + B PIPELINE.
// r15: k-split across waves (r14) was NULL — more waves/SIMD with half the
// chain each moved nothing (same lesson as attn r8). The per-iter ~2000cyc is
// per-wave-serial: the 5 Bv ds_reads are consumed immediately -> lgkmcnt
// stall (~120cyc LDS latency) every sub-iter. Fix inside the chain: dist-2
// register ping/pong for B, symmetric with the A pipeline (Bping/Bpong
// issued 2 sub-iters ahead, ~500cyc MFMA cover). +40 VGPR (~108 arch +
// 100 AGPR acc) — bare (256), 1 block/CU, no demotion at this shape (r11).
#define CTN 80
#define CROWS 89          // CTN + KSZ - 1
#define CSTRIDE 328       // 656B/row -> benign 2-way conflicts
__global__ __launch_bounds__(256) void conv_mfma_kernel(
    const int* __restrict__ ids, const float* __restrict__ embed_w,
    const unsigned short* __restrict__ wT,
    const float* __restrict__ bias, unsigned short* __restrict__ h) {
  __shared__ unsigned short xls[CROWS * CSTRIDE];   // 58384 B
  int b = blockIdx.x & 7, tb = blockIdx.x >> 3;     // grid 208 = 8 x 26
  int t0 = tb * CTN;
  int tid = threadIdx.x;
  {
    const int* idsb = ids + b * TSEQ;
    for (int idx = tid; idx < CROWS * 40; idx += 256) {
      int rr = idx / 40, c8 = idx % 40;
      int tau = t0 + rr;
      bool inr = (tau >= PADL) && (tau < PADL + TSEQ);
      unsigned short pk[8];
      if (inr) {
        int row = idsb[tau - PADL];
        const float* src = embed_w + (size_t)row * DDIM + c8 * 8;
        float4 lo = (c8 * 8 + 3 < DDIM) ? *(const float4*)&src[0] : make_float4(0, 0, 0, 0);
        float4 hi = (c8 * 8 + 7 < DDIM) ? *(const float4*)&src[4] : make_float4(0, 0, 0, 0);
        pk[0] = f2bf(lo.x); pk[1] = f2bf(lo.y); pk[2] = f2bf(lo.z); pk[3] = f2bf(lo.w);
        pk[4] = f2bf(hi.x); pk[5] = f2bf(hi.y); pk[6] = f2bf(hi.z); pk[7] = f2bf(hi.w);
      } else {
#pragma unroll
        for (int e = 0; e < 8; ++e) pk[e] = 0;
      }
      *(int4*)&xls[rr * CSTRIDE + c8 * 8] = *(const int4*)pk;
    }
  }
  __syncthreads();
  int w = tid >> 6, lane = tid & 63;
  int l15 = lane & 15, quad = lane >> 4;
  int ob = w * 80;                                  // o-quadrant per wave
  f4v acc[5][5];
#pragma unroll
  for (int mf = 0; mf < 5; ++mf) {
    float bv[4];
#pragma unroll
    for (int rr = 0; rr < 4; ++rr) {
      int o = ob + mf * 16 + quad * 4 + rr;
      bv[rr] = (o < DDIM) ? bias[o] : 0.0f;
    }
#pragma unroll
    for (int nf = 0; nf < 5; ++nf) {
      acc[mf][nf][0] = bv[0]; acc[mf][nf][1] = bv[1];
      acc[mf][nf][2] = bv[2]; acc[mf][nf][3] = bv[3];
    }
  }
  // A-frag (kc,it,mf) at wl[kc*DPAD*DPAD + mf*16*DPAD + it*32]
  // B-frag (kc,it,nf) at xls[(nf*16+l15+kc)*CSTRIDE + it*32 + quad*8]
  const unsigned short* wl = wT + (size_t)(ob + l15) * DPAD + quad * 8;
  s8v Aping[5], Apong[5], Bping[5], Bpong[5];
#pragma unroll
  for (int mf = 0; mf < 5; ++mf) Aping[mf] = *(const s8v*)&wl[mf * 16 * DPAD];        // (0,0)
#pragma unroll
  for (int mf = 0; mf < 5; ++mf) Apong[mf] = *(const s8v*)&wl[mf * 16 * DPAD + 32];   // (0,1)
#pragma unroll
  for (int nf = 0; nf < 5; ++nf) Bping[nf] = *(const s8v*)&xls[(nf * 16 + l15) * CSTRIDE + quad * 8];       // (0,0)
#pragma unroll
  for (int nf = 0; nf < 5; ++nf) Bpong[nf] = *(const s8v*)&xls[(nf * 16 + l15) * CSTRIDE + 32 + quad * 8];  // (0,1)
  for (int ii = 0; ii < 100; ii += 2) {
    // ---- even sub-iter: frags (ii) in Aping/Bping
    {
#pragma unroll
      for (int mf = 0; mf < 5; ++mf)
#pragma unroll
        for (int nf = 0; nf < 5; ++nf)
          acc[mf][nf] = __builtin_amdgcn_mfma_f32_16x16x32_bf16(Aping[mf], Bping[nf], acc[mf][nf], 0, 0, 0);
      int p = ii + 2;
      if (p < 100) {
        int kp = p / 10, itp = p % 10;
        const unsigned short* wp = wl + (size_t)kp * (DPAD * DPAD) + itp * 32;
#pragma unroll
        for (int mf = 0; mf < 5; ++mf) Aping[mf] = *(const s8v*)&wp[mf * 16 * DPAD];
#pragma unroll
        for (int nf = 0; nf < 5; ++nf)
          Bping[nf] = *(const s8v*)&xls[(nf * 16 + l15 + kp) * CSTRIDE + itp * 32 + quad * 8];
      }
    }
    // ---- odd sub-iter: frags (ii+1) in Apong/Bpong
    {
#pragma unroll
      for (int mf = 0; mf < 5; ++mf)
#pragma unroll
        for (int nf = 0; nf < 5; ++nf)
          acc[mf][nf] = __builtin_amdgcn_mfma_f32_16x16x32_bf16(Apong[mf], Bpong[nf], acc[mf][nf], 0, 0, 0);
      int p = ii + 3;
      if (p < 100) {
        int kp = p / 10, itp = p % 10;
        const unsigned short* wp = wl + (size_t)kp * (DPAD * DPAD) + itp * 32;
#pragma unroll
        for (int mf = 0; mf < 5; ++mf) Apong[mf] = *(const s8v*)&wp[mf * 16 * DPAD];
#pragma unroll
        for (int nf = 0; nf < 5; ++nf)
          Bpong[nf] = *(const s8v*)&xls[(nf * 16 + l15 + kp) * CSTRIDE + itp * 32 + quad * 8];
      }
    }
  }
#pragma unroll
  for (int mf = 0; mf < 5; ++mf) {
    int obase = ob + mf * 16 + quad * 4;
#pragma unroll
    for (int nf = 0; nf < 5; ++nf) {
      int t = t0 + nf * 16 + l15;            // always < TALLOC (26x80 = 2080 exact)
      bool live = t < TPRIME;
      unsigned short pk[4];
#pragma unroll
      for (int rr = 0; rr < 4; ++rr)
        pk[rr] = live ? f2bf(fmaxf(acc[mf][nf][rr], 0.0f)) : (unsigned short)0;
      *(uint2*)&h[((size_t)b * TALLOC + t) * DPAD + obase] = *(uint2*)pk;
    }
  }
}

// ---- K3: scores (U . h) via MFMA + fused softmax-weighted mean.
// FROZEN r5/r6/r11 local optimum (119us; best of 6 structural attempts — r6
// tweaks null, r7 T15 spilled, r8 8-wave +13, r9 no-LDS +330, r10 dist-2
// +32). 4 waves, depth-1 DMA double-buffer, vmcnt(0)+barrier per tile, all
// 560 blocks co-resident at (256,3). A[2][10] in AGPRs. Unmasked softmax
// (tail h rows exact zeros -> e=1) + (-23) phantom correction; setprio.
__global__ __launch_bounds__(256, 3) void attn_mfma_kernel(
    const unsigned short* __restrict__ h, const unsigned short* __restrict__ Ub,
    const float* __restrict__ fcb, float* __restrict__ out) {
  __shared__ unsigned short hls[2 * TSTG * DPAD];   // 2 x 10240 elems = 40960B
  int b = blockIdx.x & 7, lb = blockIdx.x >> 3;
  int tid = threadIdx.x;
  int w = tid >> 6, lane = tid & 63;
  int l15 = lane & 15, quad = lane >> 4;
  const unsigned short* hb = h + (size_t)b * TALLOC * DPAD;

  // A fragments (U): wave covers 32 l-rows
  s8v A[2][10];
  {
    int lr0 = lb * 128 + w * 32 + l15;
#pragma unroll
    for (int mf = 0; mf < 2; ++mf) {
      int lr = lr0 + mf * 16;
      if (lr >= LPAD) lr = LPAD - 1;          // clamped rows masked at store
      const unsigned short* up = Ub + (size_t)lr * DPAD + quad * 8;
#pragma unroll
      for (int kc = 0; kc < 10; ++kc)
        A[mf][kc] = *(const s8v*)&up[kc * 32];
    }
  }

  // DMA staging map: wave w fills LDS elems [w*2560, w*2560+2560) in 5 x 1KB.
  // lane's LDS chunk g = w*320 + j*64 + lane -> row r = g/40, chunk c = g%40;
  // global source chunk = c ^ (r&7)  (involution, same XOR on read side)
  int srcoff[5];
#pragma unroll
  for (int j = 0; j < 5; ++j) {
    int g = w * 320 + j * 64 + lane;
    int r = g / 40, c = g % 40;
    srcoff[j] = r * DPAD + ((c ^ (r & 7)) * 8);
  }

  // prologue: DMA tile 0 -> buf0
#pragma unroll
  for (int j = 0; j < 5; ++j)
    __builtin_amdgcn_global_load_lds((gas_ptr)(const void*)(hb + srcoff[j]),
                                     (las_ptr)(void*)&hls[w * 2560 + j * 512],
                                     16, 0, 0);
  asm volatile("s_waitcnt vmcnt(0)" ::: "memory");
  __builtin_amdgcn_s_barrier();

  float se[2][4], sw[2][4];
#pragma unroll
  for (int mf = 0; mf < 2; ++mf)
#pragma unroll
    for (int r = 0; r < 4; ++r) { se[mf][r] = 0.0f; sw[mf][r] = 0.0f; }

  int xr8 = (l15 & 7) * 8;            // read-side XOR (elem units)
  int rowb0 = l15 * DPAD;             // nf=0 row base
  int rowb1 = (16 + l15) * DPAD;      // nf=1 row base
  int bufsel = 0;
  const f4v vzero = {0.0f, 0.0f, 0.0f, 0.0f};
  for (int t = 0; t < NTT; ++t) {
    // issue DMA for tile t+1 into the other buffer (latency hidden by compute)
    if (t + 1 < NTT) {
      const unsigned short* src = hb + (size_t)(t + 1) * TSTG * DPAD;
      int dstb = (bufsel ^ 1) * 10240 + w * 2560;
#pragma unroll
      for (int j = 0; j < 5; ++j)
        __builtin_amdgcn_global_load_lds((gas_ptr)(const void*)(src + srcoff[j]),
                                         (las_ptr)(void*)&hls[dstb + j * 512],
                                         16, 0, 0);
    }
    const unsigned short* bufc = &hls[bufsel * 10240];
    f4v a00, a01, a10, a11;
    __builtin_amdgcn_s_setprio(1);
    {
      int ko = (quad * 8) ^ xr8;
      s8v Bv0 = *(const s8v*)&bufc[rowb0 + ko];
      s8v Bv1 = *(const s8v*)&bufc[rowb1 + ko];
      a00 = __builtin_amdgcn_mfma_f32_16x16x32_bf16(A[0][0], Bv0, vzero, 0, 0, 0);
      a01 = __builtin_amdgcn_mfma_f32_16x16x32_bf16(A[0][0], Bv1, vzero, 0, 0, 0);
      a10 = __builtin_amdgcn_mfma_f32_16x16x32_bf16(A[1][0], Bv0, vzero, 0, 0, 0);
      a11 = __builtin_amdgcn_mfma_f32_16x16x32_bf16(A[1][0], Bv1, vzero, 0, 0, 0);
    }
#pragma unroll
    for (int kc = 1; kc < 10; ++kc) {
      int ko = (kc * 32 + quad * 8) ^ xr8;
      s8v Bv0 = *(const s8v*)&bufc[rowb0 + ko];
      s8v Bv1 = *(const s8v*)&bufc[rowb1 + ko];
      a00 = __builtin_amdgcn_mfma_f32_16x16x32_bf16(A[0][kc], Bv0, a00, 0, 0, 0);
      a01 = __builtin_amdgcn_mfma_f32_16x16x32_bf16(A[0][kc], Bv1, a01, 0, 0, 0);
      a10 = __builtin_amdgcn_mfma_f32_16x16x32_bf16(A[1][kc], Bv0, a10, 0, 0, 0);
      a11 = __builtin_amdgcn_mfma_f32_16x16x32_bf16(A[1][kc], Bv1, a11, 0, 0, 0);
    }
    __builtin_amdgcn_s_setprio(0);
    // unmasked fused softmax accumulation (tail h rows are exact zeros ->
    // s=0 -> e=1; corrected after the reduction)
#pragma unroll
    for (int r = 0; r < 4; ++r) {
      float s0 = a00[r], s1 = a01[r];
      float e0 = __expf(s0), e1 = __expf(s1);
      se[0][r] += e0 + e1;
      sw[0][r] = fmaf(e0, s0, sw[0][r]);
      sw[0][r] = fmaf(e1, s1, sw[0][r]);
      float s2 = a10[r], s3 = a11[r];
      float e2 = __expf(s2), e3 = __expf(s3);
      se[1][r] += e2 + e3;
      sw[1][r] = fmaf(e2, s2, sw[1][r]);
      sw[1][r] = fmaf(e3, s3, sw[1][r]);
    }
    // drain this iter's DMA (issued a full tile of compute ago), sync, swap
    asm volatile("s_waitcnt vmcnt(0)" ::: "memory");
    __builtin_amdgcn_s_barrier();
    bufsel ^= 1;
  }

  // reduce over the 16 t-columns (l15 lanes); subtract the 23 phantom columns
  // (TALLOC - TPRIME, each contributing exactly exp(0)=1) from the denominator.
#pragma unroll
  for (int mf = 0; mf < 2; ++mf)
#pragma unroll
    for (int r = 0; r < 4; ++r) {
      float a = se[mf][r], c = sw[mf][r];
#pragma unroll
      for (int off = 1; off < 16; off <<= 1) {
        a += __shfl_xor(a, off, 64);
        c += __shfl_xor(c, off, 64);
      }
      if (l15 == 0) {
        int l = lb * 128 + w * 32 + mf * 16 + quad * 4 + r;
        if (l < LDIM) out[(size_t)b * LDIM + l] = c / (a - 23.0f) + fcb[l];
      }
    }
}

extern "C" void kernel_launch(void* const* d_in, const int* in_sizes, int n_in,
                              void* d_out, int out_size, void* d_ws, size_t ws_size,
                              hipStream_t stream) {
  const int*   ids     = (const int*)d_in[0];
  const float* embed_w = (const float*)d_in[1];
  const float* conv_w  = (const float*)d_in[2];
  const float* conv_b  = (const float*)d_in[3];
  const float* U       = (const float*)d_in[4];
  const float* fc_bias = (const float*)d_in[5];
  float* out = (float*)d_out;

  unsigned char* p = (unsigned char*)d_ws;
  unsigned short* hb = (unsigned short*)p;                 p += (size_t)BATCH * TALLOC * DPAD * 2;
  unsigned short* wT = (unsigned short*)p;                 p += (size_t)KSZ * DPAD * DPAD * 2;
  unsigned short* Ub = (unsigned short*)p;

  hipLaunchKernelGGL(prep_kernel, dim3(KSZ * DPAD + LPAD), dim3(256), 0, stream,
                     conv_w, U, wT, Ub);
  hipLaunchKernelGGL(conv_mfma_kernel, dim3(BATCH * 26), dim3(256), 0, stream,
                     ids, embed_w, wT, conv_b, hb);
  hipLaunchKernelGGL(attn_mfma_kernel, dim3(BATCH * LBLK), dim3(256), 0, stream,
                     hb, Ub, fc_bias, out);
}